// Round 10
// baseline (584.989 us; speedup 1.0000x reference)
//
#include <hip/hip_runtime.h>

typedef unsigned short u16;
typedef unsigned int u32;
typedef __bf16 bf16x8 __attribute__((ext_vector_type(8)));
typedef float f32x4 __attribute__((ext_vector_type(4)));
typedef float f32x16 __attribute__((ext_vector_type(16)));

#define D_EMB 1024
#define T_SEQ 2048
#define NH 16
#define HD 64
#define GRID_N 768u

#define GLB(p) ((const __attribute__((address_space(1))) unsigned int*)(p))
#define LDSP(p) ((__attribute__((address_space(3))) unsigned int*)(p))

__device__ __forceinline__ u16 f2bf(float f) {
  union { float f; unsigned u; } c; c.f = f;
  unsigned u = c.u;
  unsigned r = (u + 0x7FFFu + ((u >> 16) & 1u)) >> 16;
  return (u16)r;
}
__device__ __forceinline__ u32 fbits(float f) {
  union { float f; unsigned u; } c; c.f = f; return c.u;
}

// Grid barrier, all GRID_N blocks co-resident (3 blocks/CU exact fit).
// Thread-0-only fences: REL fetch_add emits s_waitcnt+buffer_wbl2 (block's writes
// are already in this XCD's L2 via write-through L1 + the vmcnt(0) drain at
// __syncthreads); ACQ spin-load emits buffer_inv invalidating this CU's L1 and
// stale XCD-L2 lines — covers all waves of the block (same CU/XCD).
__device__ __forceinline__ void gridbar(u32* cnt, u32 target) {
  __syncthreads();
  if (threadIdx.x == 0) {
    __hip_atomic_fetch_add(cnt, 1u, __ATOMIC_RELEASE, __HIP_MEMORY_SCOPE_AGENT);
    while (__hip_atomic_load(cnt, __ATOMIC_ACQUIRE, __HIP_MEMORY_SCOPE_AGENT) < target)
      __builtin_amdgcn_s_sleep(8);
  }
  __syncthreads();
}

// ================= mega kernel: prep -> proj -> attn -> oproj =================
__global__ __launch_bounds__(256, 3) void mega_kernel(
    const float* __restrict__ x, const float* __restrict__ e,
    const float* __restrict__ W_q, const float* __restrict__ W_en, const float* __restrict__ W_o,
    u16* __restrict__ xb, u16* __restrict__ eb,
    u16* __restrict__ Wqt, u16* __restrict__ Went, u16* __restrict__ Wot,
    u16* __restrict__ qw, u16* __restrict__ kw, u16* __restrict__ vTw,
    u16* __restrict__ yw, float* __restrict__ out, u32* __restrict__ bar) {
  __shared__ __align__(16) char smem[49152];
  const int bid = blockIdx.x;
  const int tid = threadIdx.x;
  const int wave = tid >> 6, lane = tid & 63;
  const int ln15 = lane & 15, quad = lane >> 4;

  // ---------------- phase 0: prep (grid-stride over 12288 units) ----------------
  {
    float* tile = (float*)smem;  // [32][33]
    for (u32 u = (u32)bid; u < 12288u; u += GRID_N) {
      if (u < 8192u) {
        const float* in = (u < 4096u) ? x : e;
        u16* outp = (u < 4096u) ? xb : eb;
        int i = (int)(u & 4095u) * 256 + tid;
        float4 v = reinterpret_cast<const float4*>(in)[i];
        ushort4 o;
        o.x = f2bf(v.x); o.y = f2bf(v.y); o.z = f2bf(v.z); o.w = f2bf(v.w);
        reinterpret_cast<ushort4*>(outp)[i] = o;
      } else {
        const float* in; u16* outp; int K, N, bx, by;
        int rem = (int)u - 8192;
        if (rem < 1024)      { in = W_q;  outp = Wqt;  K = 1024; N = 1024; bx = rem & 31; by = rem >> 5; }
        else if (rem < 3072) { int r2 = rem - 1024; in = W_en; outp = Went; K = 1024; N = 2048; bx = r2 & 63; by = r2 >> 6; }
        else                 { int r3 = rem - 3072; in = W_o;  outp = Wot;  K = 1024; N = 1024; bx = r3 & 31; by = r3 >> 5; }
        int tx = tid & 31, ty = tid >> 5;
        int n0 = bx * 32, k0 = by * 32;
        __syncthreads();   // protect tile across grid-stride iterations (uniform branch)
#pragma unroll
        for (int s = 0; s < 4; s++)
          tile[(ty + 8 * s) * 33 + tx] = in[(size_t)(k0 + ty + 8 * s) * N + n0 + tx];
        __syncthreads();
#pragma unroll
        for (int s = 0; s < 4; s++)
          outp[(size_t)(n0 + ty + 8 * s) * K + k0 + tx] = f2bf(tile[tx * 33 + ty + 8 * s]);
      }
    }
  }
  gridbar(bar, GRID_N);

  // ---------------- phase 1: proj (768 tiles, 1:1) ----------------
  {
    u16* Al0 = (u16*)(smem);
    u16* Bl0 = (u16*)(smem + 8192);
    u16* Al1 = (u16*)(smem + 16384);
    u16* Bl1 = (u16*)(smem + 24576);
    const int nb = bid % 24, mb = bid / 24;
    const int wm = wave & 1, wn = wave >> 1;

    const u16* A = (nb < 8) ? xb : eb;
    const u16* Wt = (nb < 8) ? (Wqt + (size_t)nb * 128 * D_EMB)
                             : (Went + ((size_t)nb * 128 - D_EMB) * D_EMB);

    const int srow = lane >> 2, sch = lane & 3;
    const int gch = sch ^ ((srow >> 1) & 3);
    const u16* gA = A + (size_t)(mb * 128 + wave * 32 + srow) * D_EMB + gch * 8;
    const u16* gB = Wt + (size_t)(wave * 32 + srow) * D_EMB + gch * 8;

    auto stage = [&](int kb, u16* AL, u16* BL) {
      char* lA = (char*)AL + wave * 2048;
      char* lB = (char*)BL + wave * 2048;
#pragma unroll
      for (int it = 0; it < 2; it++) {
        __builtin_amdgcn_global_load_lds(GLB(gA + (size_t)it * 16 * D_EMB + kb), LDSP(lA + it * 1024), 16, 0, 0);
        __builtin_amdgcn_global_load_lds(GLB(gB + (size_t)it * 16 * D_EMB + kb), LDSP(lB + it * 1024), 16, 0, 0);
      }
    };

    f32x4 acc[4][4] = {};
    auto compute = [&](const u16* AL, const u16* BL) {
      bf16x8 af[4], bfr[4];
#pragma unroll
      for (int mt = 0; mt < 4; mt++) {
        int r = wm * 64 + mt * 16 + ln15;
        af[mt] = *reinterpret_cast<const bf16x8*>(&AL[r * 32 + ((quad ^ ((r >> 1) & 3)) * 8)]);
      }
#pragma unroll
      for (int nt = 0; nt < 4; nt++) {
        int r = wn * 64 + nt * 16 + ln15;
        bfr[nt] = *reinterpret_cast<const bf16x8*>(&BL[r * 32 + ((quad ^ ((r >> 1) & 3)) * 8)]);
      }
#pragma unroll
      for (int mt = 0; mt < 4; mt++)
#pragma unroll
        for (int nt = 0; nt < 4; nt++)
          acc[mt][nt] = __builtin_amdgcn_mfma_f32_16x16x32_bf16(af[mt], bfr[nt], acc[mt][nt], 0, 0, 0);
    };

    stage(0, Al0, Bl0);
    for (int kb = 0; kb < D_EMB; kb += 64) {
      __syncthreads();
      stage(kb + 32, Al1, Bl1);
      compute(Al0, Bl0);
      __syncthreads();
      if (kb + 64 < D_EMB) stage(kb + 64, Al0, Bl0);
      compute(Al1, Bl1);
    }

    const float QSCL = 0.125f * 1.44269504f;
#pragma unroll
    for (int mt = 0; mt < 4; mt++) {
#pragma unroll
      for (int nt = 0; nt < 4; nt++) {
#pragma unroll
        for (int i = 0; i < 4; i++) {
          int rr = mb * 128 + wm * 64 + mt * 16 + quad * 4 + i;
          int c  = nb * 128 + wn * 64 + nt * 16 + ln15;
          float v = acc[mt][nt][i];
          int b = rr >> 11, t = rr & 2047;
          if (c < D_EMB) {
            int h = c >> 6, d = c & 63;
            qw[(((size_t)(b * NH + h)) * T_SEQ + t) * HD + d] = f2bf(v * QSCL);
          } else if (c < 2 * D_EMB) {
            int cc = c - D_EMB; int h = cc >> 6, d = cc & 63;
            kw[(((size_t)(b * NH + h)) * T_SEQ + t) * HD + d] = f2bf(v);
          } else {
            int cc = c - 2 * D_EMB; int h = cc >> 6, d = cc & 63;
            vTw[(((size_t)(b * NH + h)) * HD + d) * T_SEQ + t] = f2bf(v);
          }
        }
      }
    }
  }
  gridbar(bar, 2 * GRID_N);

  // ---------------- phase 2: attn (512 active blocks) ----------------
  if (bid < 512) {
    u16 (*Kl0)[64] = (u16(*)[64])(smem);
    u16 (*Vl0)[64] = (u16(*)[64])(smem + 8192);
    u16 (*Kl1)[64] = (u16(*)[64])(smem + 16384);
    u16 (*Vl1)[64] = (u16(*)[64])(smem + 24576);
    u16* Pl = (u16*)(smem + 32768);   // [4][32][64]

    const int qt = bid & 15, bh = bid >> 4;
    const int q32 = lane & 31, hi = lane >> 5;
    const int b = bh >> 4, h = bh & 15;

    const int qrow = qt * 128 + wave * 32 + q32;
    const u16* qbase = qw + ((size_t)bh * T_SEQ + qrow) * HD;
    bf16x8 qf[4];
#pragma unroll
    for (int s = 0; s < 4; s++)
      qf[s] = *reinterpret_cast<const bf16x8*>(qbase + s * 16 + hi * 8);

    f32x16 o2[2] = {};
    float lp = 0.f;

    const int srow = (lane >> 3) & 7;
    const int gch  = (lane & 7) ^ srow;
    const u16* kg0 = kw  + ((size_t)bh * T_SEQ + wave * 16 + srow) * HD + gch * 8;
    const u16* vg0 = vTw + ((size_t)bh * HD + wave * 16 + srow) * T_SEQ + gch * 8;

    auto issue_dma = [&](int t, u16 (*KL)[64], u16 (*VL)[64]) {
      char* klb = (char*)KL + wave * 2048;
      char* vlb = (char*)VL + wave * 2048;
      const u16* kp = kg0 + (size_t)t * 64 * HD;
      const u16* vp = vg0 + t * 64;
      __builtin_amdgcn_global_load_lds(GLB(kp),             LDSP(klb),        16, 0, 0);
      __builtin_amdgcn_global_load_lds(GLB(kp + 8 * HD),    LDSP(klb + 1024), 16, 0, 0);
      __builtin_amdgcn_global_load_lds(GLB(vp),             LDSP(vlb),        16, 0, 0);
      __builtin_amdgcn_global_load_lds(GLB(vp + 8 * T_SEQ), LDSP(vlb + 1024), 16, 0, 0);
    };

    auto body = [&](const u16 (*KL)[64], const u16 (*VL)[64]) {
      f32x16 s2[2] = {};
#pragma unroll
      for (int s = 0; s < 4; s++)
#pragma unroll
        for (int kt2 = 0; kt2 < 2; kt2++) {
          int r = kt2 * 32 + q32;
          bf16x8 kf = *reinterpret_cast<const bf16x8*>(&KL[r][(((s * 2 + hi) ^ (r & 7)) * 8)]);
          s2[kt2] = __builtin_amdgcn_mfma_f32_32x32x16_bf16(kf, qf[s], s2[kt2], 0, 0, 0);
        }
#pragma unroll
      for (int kt2 = 0; kt2 < 2; kt2++)
#pragma unroll
        for (int g = 0; g < 4; g++) {
          float p0 = __builtin_amdgcn_exp2f(s2[kt2][4 * g + 0]);
          float p1 = __builtin_amdgcn_exp2f(s2[kt2][4 * g + 1]);
          float p2 = __builtin_amdgcn_exp2f(s2[kt2][4 * g + 2]);
          float p3 = __builtin_amdgcn_exp2f(s2[kt2][4 * g + 3]);
          lp += (p0 + p1) + (p2 + p3);
          u32 dw0 = __builtin_amdgcn_perm(fbits(p1), fbits(p0), 0x07060302u);
          u32 dw1 = __builtin_amdgcn_perm(fbits(p3), fbits(p2), 0x07060302u);
          int phys = (kt2 * 4 + g) ^ (q32 & 7);
          *reinterpret_cast<uint2*>(&Pl[(wave * 32 + q32) * 64 + phys * 8 + 4 * hi]) = make_uint2(dw0, dw1);
        }
      asm volatile("s_waitcnt lgkmcnt(0)" ::: "memory");
#pragma unroll
      for (int s = 0; s < 4; s++) {
        bf16x8 pf = *reinterpret_cast<const bf16x8*>(
            &Pl[(wave * 32 + q32) * 64 + (((s * 2 + hi) ^ (q32 & 7)) * 8)]);
#pragma unroll
        for (int dt = 0; dt < 2; dt++) {
          int r = dt * 32 + q32;
          bf16x8 vf = *reinterpret_cast<const bf16x8*>(&VL[r][(((s * 2 + hi) ^ (r & 7)) * 8)]);
          o2[dt] = __builtin_amdgcn_mfma_f32_32x32x16_bf16(vf, pf, o2[dt], 0, 0, 0);
        }
      }
    };

    issue_dma(0, Kl0, Vl0);
    for (int t = 0; t < 32; t += 2) {
      __syncthreads();
      issue_dma(t + 1, Kl1, Vl1);
      body(Kl0, Vl0);
      __syncthreads();
      if (t + 2 < 32) issue_dma(t + 2, Kl0, Vl0);
      body(Kl1, Vl1);
    }

    lp += __shfl_xor(lp, 32, 64);
    const float inv = 1.0f / lp;
    const size_t ybase = ((size_t)b * T_SEQ + qrow) * D_EMB + h * 64;
#pragma unroll
    for (int dt = 0; dt < 2; dt++)
#pragma unroll
      for (int g = 0; g < 4; g++) {
        u16 b0 = f2bf(o2[dt][4 * g + 0] * inv), b1 = f2bf(o2[dt][4 * g + 1] * inv);
        u16 b2 = f2bf(o2[dt][4 * g + 2] * inv), b3 = f2bf(o2[dt][4 * g + 3] * inv);
        u32 dw0 = (u32)b0 | ((u32)b1 << 16);
        u32 dw1 = (u32)b2 | ((u32)b3 << 16);
        *reinterpret_cast<uint2*>(&yw[ybase + dt * 32 + 8 * g + 4 * hi]) = make_uint2(dw0, dw1);
      }
  }
  gridbar(bar, 3 * GRID_N);

  // ---------------- phase 3: oproj (512 active blocks) ----------------
  if (bid < 512) {
    u16* Al0 = (u16*)(smem);
    u16* Al1 = (u16*)(smem + 4096);
    u16* Bl0 = (u16*)(smem + 8192);
    u16* Bl1 = (u16*)(smem + 16384);
    const int nb = bid & 7, mb = bid >> 3;
    const int wm = wave & 1, wn = wave >> 1;

    const int srow = lane >> 2, sch = lane & 3;
    const int gch = sch ^ ((srow >> 1) & 3);
    const u16* gA = yw  + (size_t)(mb * 64 + wave * 16 + srow) * D_EMB + gch * 8;
    const u16* gB = Wot + (size_t)(nb * 128 + wave * 32 + srow) * D_EMB + gch * 8;

    auto stage = [&](int kb, u16* AL, u16* BL) {
      char* lA = (char*)AL + wave * 1024;
      char* lB = (char*)BL + wave * 2048;
      __builtin_amdgcn_global_load_lds(GLB(gA + kb), LDSP(lA), 16, 0, 0);
#pragma unroll
      for (int it = 0; it < 2; it++)
        __builtin_amdgcn_global_load_lds(GLB(gB + (size_t)it * 16 * D_EMB + kb), LDSP(lB + it * 1024), 16, 0, 0);
    };

    f32x4 acc[2][4] = {};
    auto compute = [&](const u16* AL, const u16* BL) {
      bf16x8 af[2], bfr[4];
#pragma unroll
      for (int mt = 0; mt < 2; mt++) {
        int r = wm * 32 + mt * 16 + ln15;
        af[mt] = *reinterpret_cast<const bf16x8*>(&AL[r * 32 + ((quad ^ ((r >> 1) & 3)) * 8)]);
      }
#pragma unroll
      for (int nt = 0; nt < 4; nt++) {
        int r = wn * 64 + nt * 16 + ln15;
        bfr[nt] = *reinterpret_cast<const bf16x8*>(&BL[r * 32 + ((quad ^ ((r >> 1) & 3)) * 8)]);
      }
#pragma unroll
      for (int mt = 0; mt < 2; mt++)
#pragma unroll
        for (int nt = 0; nt < 4; nt++)
          acc[mt][nt] = __builtin_amdgcn_mfma_f32_16x16x32_bf16(af[mt], bfr[nt], acc[mt][nt], 0, 0, 0);
    };

    stage(0, Al0, Bl0);
    for (int kb = 0; kb < D_EMB; kb += 64) {
      __syncthreads();
      stage(kb + 32, Al1, Bl1);
      compute(Al0, Bl0);
      __syncthreads();
      if (kb + 64 < D_EMB) stage(kb + 64, Al0, Bl0);
      compute(Al1, Bl1);
    }

#pragma unroll
    for (int mt = 0; mt < 2; mt++)
#pragma unroll
      for (int nt = 0; nt < 4; nt++)
#pragma unroll
        for (int i = 0; i < 4; i++) {
          int rr = mb * 64 + wm * 32 + mt * 16 + quad * 4 + i;
          int c  = nb * 128 + wn * 64 + nt * 16 + ln15;
          out[(size_t)rr * D_EMB + c] = acc[mt][nt][i];
        }
  }
}

extern "C" void kernel_launch(void* const* d_in, const int* in_sizes, int n_in,
                              void* d_out, int out_size, void* d_ws, size_t ws_size,
                              hipStream_t stream) {
  const float* x    = (const float*)d_in[0];
  const float* e    = (const float*)d_in[1];
  const float* W_en = (const float*)d_in[2];
  const float* W_q  = (const float*)d_in[3];
  const float* W_o  = (const float*)d_in[4];
  float* out = (float*)d_out;

  // Layout (48 MB + 64 B high-water, well inside the proven-available 56 MB):
  // [0,8) xb (phase 0/1) ALIASED with yw (phase 2/3) — lifetimes barrier-separated.
  char* w = (char*)d_ws;
  u16* xb   = (u16*)(w);                 // phases 0-1
  u16* yw   = (u16*)(w);                 // phases 2-3 (alias, dead xb)
  u16* eb   = (u16*)(w + (8u  << 20));
  u16* Wqt  = (u16*)(w + (16u << 20));
  u16* Went = (u16*)(w + (18u << 20));
  u16* Wot  = (u16*)(w + (22u << 20));
  u16* qw   = (u16*)(w + (24u << 20));
  u16* kw   = (u16*)(w + (32u << 20));
  u16* vT   = (u16*)(w + (40u << 20));
  u32* bar  = (u32*)(w + (48u << 20));   // in-bounds barrier counter

  hipMemsetAsync(bar, 0, 64, stream);    // zero counter each launch (graph-safe)
  mega_kernel<<<GRID_N, 256, 0, stream>>>(x, e, W_q, W_en, W_o,
                                          xb, eb, Wqt, Went, Wot,
                                          qw, kw, vT, yw, out, bar);
}

// Round 11
// 451.758 us; speedup vs baseline: 1.2949x; 1.2949x over previous
//
#include <hip/hip_runtime.h>

typedef unsigned short u16;
typedef unsigned int u32;
typedef __bf16 bf16x8 __attribute__((ext_vector_type(8)));
typedef float f32x4 __attribute__((ext_vector_type(4)));
typedef float f32x16 __attribute__((ext_vector_type(16)));

#define D_EMB 1024
#define T_SEQ 2048
#define NH 16
#define HD 64
#define GRID_N 768u

#define GLB(p) ((const __attribute__((address_space(1))) unsigned int*)(p))
#define LDSP(p) ((__attribute__((address_space(3))) unsigned int*)(p))

__device__ __forceinline__ u16 f2bf(float f) {
  union { float f; unsigned u; } c; c.f = f;
  unsigned u = c.u;
  unsigned r = (u + 0x7FFFu + ((u >> 16) & 1u)) >> 16;
  return (u16)r;
}
__device__ __forceinline__ u32 fbits(float f) {
  union { float f; unsigned u; } c; c.f = f; return c.u;
}

// Grid barrier, all GRID_N blocks co-resident (3 blocks/CU exact fit).
// RELAXED polling (no cache side-effects while spinning!) + ONE acquire after
// the count is reached. R10's per-poll ACQUIRE caused an L1/L2 invalidate storm
// (FETCH 197 MB, 585 us); release/acquire is needed once per crossing only.
__device__ __forceinline__ void gridbar(u32* cnt, u32 target) {
  __syncthreads();
  if (threadIdx.x == 0) {
    __hip_atomic_fetch_add(cnt, 1u, __ATOMIC_RELEASE, __HIP_MEMORY_SCOPE_AGENT);
    while (__hip_atomic_load(cnt, __ATOMIC_RELAXED, __HIP_MEMORY_SCOPE_AGENT) < target)
      __builtin_amdgcn_s_sleep(16);
    (void)__hip_atomic_load(cnt, __ATOMIC_ACQUIRE, __HIP_MEMORY_SCOPE_AGENT); // one inv
  }
  __syncthreads();
}

// ================= mega kernel: prep -> proj -> attn -> oproj =================
__global__ __launch_bounds__(256, 3) void mega_kernel(
    const float* __restrict__ x, const float* __restrict__ e,
    const float* __restrict__ W_q, const float* __restrict__ W_en, const float* __restrict__ W_o,
    u16* __restrict__ xb, u16* __restrict__ eb,
    u16* __restrict__ Wqt, u16* __restrict__ Went, u16* __restrict__ Wot,
    u16* __restrict__ qw, u16* __restrict__ kw, u16* __restrict__ vTw,
    u16* __restrict__ yw, float* __restrict__ out, u32* __restrict__ bar) {
  __shared__ __align__(16) char smem[49152];
  const int bid = blockIdx.x;
  const int tid = threadIdx.x;
  const int wave = tid >> 6, lane = tid & 63;
  const int ln15 = lane & 15, quad = lane >> 4;

  // ---------------- phase 0: prep (grid-stride over 12288 units) ----------------
  {
    float* tile = (float*)smem;  // [32][33]
    for (u32 u = (u32)bid; u < 12288u; u += GRID_N) {
      if (u < 8192u) {
        const float* in = (u < 4096u) ? x : e;
        u16* outp = (u < 4096u) ? xb : eb;
        int i = (int)(u & 4095u) * 256 + tid;
        float4 v = reinterpret_cast<const float4*>(in)[i];
        ushort4 o;
        o.x = f2bf(v.x); o.y = f2bf(v.y); o.z = f2bf(v.z); o.w = f2bf(v.w);
        reinterpret_cast<ushort4*>(outp)[i] = o;
      } else {
        const float* in; u16* outp; int K, N, bx, by;
        int rem = (int)u - 8192;
        if (rem < 1024)      { in = W_q;  outp = Wqt;  K = 1024; N = 1024; bx = rem & 31; by = rem >> 5; }
        else if (rem < 3072) { int r2 = rem - 1024; in = W_en; outp = Went; K = 1024; N = 2048; bx = r2 & 63; by = r2 >> 6; }
        else                 { int r3 = rem - 3072; in = W_o;  outp = Wot;  K = 1024; N = 1024; bx = r3 & 31; by = r3 >> 5; }
        int tx = tid & 31, ty = tid >> 5;
        int n0 = bx * 32, k0 = by * 32;
        __syncthreads();   // protect tile across grid-stride iterations (uniform branch)
#pragma unroll
        for (int s = 0; s < 4; s++)
          tile[(ty + 8 * s) * 33 + tx] = in[(size_t)(k0 + ty + 8 * s) * N + n0 + tx];
        __syncthreads();
#pragma unroll
        for (int s = 0; s < 4; s++)
          outp[(size_t)(n0 + ty + 8 * s) * K + k0 + tx] = f2bf(tile[tx * 33 + ty + 8 * s]);
      }
    }
  }
  gridbar(bar, GRID_N);

  // ---------------- phase 1: proj (768 tiles, 1:1) ----------------
  {
    u16* Al0 = (u16*)(smem);
    u16* Bl0 = (u16*)(smem + 8192);
    u16* Al1 = (u16*)(smem + 16384);
    u16* Bl1 = (u16*)(smem + 24576);
    const int nb = bid % 24, mb = bid / 24;
    const int wm = wave & 1, wn = wave >> 1;

    const u16* A = (nb < 8) ? xb : eb;
    const u16* Wt = (nb < 8) ? (Wqt + (size_t)nb * 128 * D_EMB)
                             : (Went + ((size_t)nb * 128 - D_EMB) * D_EMB);

    const int srow = lane >> 2, sch = lane & 3;
    const int gch = sch ^ ((srow >> 1) & 3);
    const u16* gA = A + (size_t)(mb * 128 + wave * 32 + srow) * D_EMB + gch * 8;
    const u16* gB = Wt + (size_t)(wave * 32 + srow) * D_EMB + gch * 8;

    auto stage = [&](int kb, u16* AL, u16* BL) {
      char* lA = (char*)AL + wave * 2048;
      char* lB = (char*)BL + wave * 2048;
#pragma unroll
      for (int it = 0; it < 2; it++) {
        __builtin_amdgcn_global_load_lds(GLB(gA + (size_t)it * 16 * D_EMB + kb), LDSP(lA + it * 1024), 16, 0, 0);
        __builtin_amdgcn_global_load_lds(GLB(gB + (size_t)it * 16 * D_EMB + kb), LDSP(lB + it * 1024), 16, 0, 0);
      }
    };

    f32x4 acc[4][4] = {};
    auto compute = [&](const u16* AL, const u16* BL) {
      bf16x8 af[4], bfr[4];
#pragma unroll
      for (int mt = 0; mt < 4; mt++) {
        int r = wm * 64 + mt * 16 + ln15;
        af[mt] = *reinterpret_cast<const bf16x8*>(&AL[r * 32 + ((quad ^ ((r >> 1) & 3)) * 8)]);
      }
#pragma unroll
      for (int nt = 0; nt < 4; nt++) {
        int r = wn * 64 + nt * 16 + ln15;
        bfr[nt] = *reinterpret_cast<const bf16x8*>(&BL[r * 32 + ((quad ^ ((r >> 1) & 3)) * 8)]);
      }
#pragma unroll
      for (int mt = 0; mt < 4; mt++)
#pragma unroll
        for (int nt = 0; nt < 4; nt++)
          acc[mt][nt] = __builtin_amdgcn_mfma_f32_16x16x32_bf16(af[mt], bfr[nt], acc[mt][nt], 0, 0, 0);
    };

    stage(0, Al0, Bl0);
    for (int kb = 0; kb < D_EMB; kb += 64) {
      __syncthreads();
      stage(kb + 32, Al1, Bl1);
      compute(Al0, Bl0);
      __syncthreads();
      if (kb + 64 < D_EMB) stage(kb + 64, Al0, Bl0);
      compute(Al1, Bl1);
    }

    const float QSCL = 0.125f * 1.44269504f;
#pragma unroll
    for (int mt = 0; mt < 4; mt++) {
#pragma unroll
      for (int nt = 0; nt < 4; nt++) {
#pragma unroll
        for (int i = 0; i < 4; i++) {
          int rr = mb * 128 + wm * 64 + mt * 16 + quad * 4 + i;
          int c  = nb * 128 + wn * 64 + nt * 16 + ln15;
          float v = acc[mt][nt][i];
          int b = rr >> 11, t = rr & 2047;
          if (c < D_EMB) {
            int h = c >> 6, d = c & 63;
            qw[(((size_t)(b * NH + h)) * T_SEQ + t) * HD + d] = f2bf(v * QSCL);
          } else if (c < 2 * D_EMB) {
            int cc = c - D_EMB; int h = cc >> 6, d = cc & 63;
            kw[(((size_t)(b * NH + h)) * T_SEQ + t) * HD + d] = f2bf(v);
          } else {
            int cc = c - 2 * D_EMB; int h = cc >> 6, d = cc & 63;
            vTw[(((size_t)(b * NH + h)) * HD + d) * T_SEQ + t] = f2bf(v);
          }
        }
      }
    }
  }
  gridbar(bar, 2 * GRID_N);

  // ---------------- phase 2: attn (512 active blocks) ----------------
  if (bid < 512) {
    u16 (*Kl0)[64] = (u16(*)[64])(smem);
    u16 (*Vl0)[64] = (u16(*)[64])(smem + 8192);
    u16 (*Kl1)[64] = (u16(*)[64])(smem + 16384);
    u16 (*Vl1)[64] = (u16(*)[64])(smem + 24576);
    u16* Pl = (u16*)(smem + 32768);   // [4][32][64]

    const int qt = bid & 15, bh = bid >> 4;
    const int q32 = lane & 31, hi = lane >> 5;
    const int b = bh >> 4, h = bh & 15;

    const int qrow = qt * 128 + wave * 32 + q32;
    const u16* qbase = qw + ((size_t)bh * T_SEQ + qrow) * HD;
    bf16x8 qf[4];
#pragma unroll
    for (int s = 0; s < 4; s++)
      qf[s] = *reinterpret_cast<const bf16x8*>(qbase + s * 16 + hi * 8);

    f32x16 o2[2] = {};
    float lp = 0.f;

    const int srow = (lane >> 3) & 7;
    const int gch  = (lane & 7) ^ srow;
    const u16* kg0 = kw  + ((size_t)bh * T_SEQ + wave * 16 + srow) * HD + gch * 8;
    const u16* vg0 = vTw + ((size_t)bh * HD + wave * 16 + srow) * T_SEQ + gch * 8;

    auto issue_dma = [&](int t, u16 (*KL)[64], u16 (*VL)[64]) {
      char* klb = (char*)KL + wave * 2048;
      char* vlb = (char*)VL + wave * 2048;
      const u16* kp = kg0 + (size_t)t * 64 * HD;
      const u16* vp = vg0 + t * 64;
      __builtin_amdgcn_global_load_lds(GLB(kp),             LDSP(klb),        16, 0, 0);
      __builtin_amdgcn_global_load_lds(GLB(kp + 8 * HD),    LDSP(klb + 1024), 16, 0, 0);
      __builtin_amdgcn_global_load_lds(GLB(vp),             LDSP(vlb),        16, 0, 0);
      __builtin_amdgcn_global_load_lds(GLB(vp + 8 * T_SEQ), LDSP(vlb + 1024), 16, 0, 0);
    };

    auto body = [&](const u16 (*KL)[64], const u16 (*VL)[64]) {
      f32x16 s2[2] = {};
#pragma unroll
      for (int s = 0; s < 4; s++)
#pragma unroll
        for (int kt2 = 0; kt2 < 2; kt2++) {
          int r = kt2 * 32 + q32;
          bf16x8 kf = *reinterpret_cast<const bf16x8*>(&KL[r][(((s * 2 + hi) ^ (r & 7)) * 8)]);
          s2[kt2] = __builtin_amdgcn_mfma_f32_32x32x16_bf16(kf, qf[s], s2[kt2], 0, 0, 0);
        }
#pragma unroll
      for (int kt2 = 0; kt2 < 2; kt2++)
#pragma unroll
        for (int g = 0; g < 4; g++) {
          float p0 = __builtin_amdgcn_exp2f(s2[kt2][4 * g + 0]);
          float p1 = __builtin_amdgcn_exp2f(s2[kt2][4 * g + 1]);
          float p2 = __builtin_amdgcn_exp2f(s2[kt2][4 * g + 2]);
          float p3 = __builtin_amdgcn_exp2f(s2[kt2][4 * g + 3]);
          lp += (p0 + p1) + (p2 + p3);
          u32 dw0 = __builtin_amdgcn_perm(fbits(p1), fbits(p0), 0x07060302u);
          u32 dw1 = __builtin_amdgcn_perm(fbits(p3), fbits(p2), 0x07060302u);
          int phys = (kt2 * 4 + g) ^ (q32 & 7);
          *reinterpret_cast<uint2*>(&Pl[(wave * 32 + q32) * 64 + phys * 8 + 4 * hi]) = make_uint2(dw0, dw1);
        }
      asm volatile("s_waitcnt lgkmcnt(0)" ::: "memory");
#pragma unroll
      for (int s = 0; s < 4; s++) {
        bf16x8 pf = *reinterpret_cast<const bf16x8*>(
            &Pl[(wave * 32 + q32) * 64 + (((s * 2 + hi) ^ (q32 & 7)) * 8)]);
#pragma unroll
        for (int dt = 0; dt < 2; dt++) {
          int r = dt * 32 + q32;
          bf16x8 vf = *reinterpret_cast<const bf16x8*>(&VL[r][(((s * 2 + hi) ^ (r & 7)) * 8)]);
          o2[dt] = __builtin_amdgcn_mfma_f32_32x32x16_bf16(vf, pf, o2[dt], 0, 0, 0);
        }
      }
    };

    issue_dma(0, Kl0, Vl0);
    for (int t = 0; t < 32; t += 2) {
      __syncthreads();
      issue_dma(t + 1, Kl1, Vl1);
      body(Kl0, Vl0);
      __syncthreads();
      if (t + 2 < 32) issue_dma(t + 2, Kl0, Vl0);
      body(Kl1, Vl1);
    }

    lp += __shfl_xor(lp, 32, 64);
    const float inv = 1.0f / lp;
    const size_t ybase = ((size_t)b * T_SEQ + qrow) * D_EMB + h * 64;
#pragma unroll
    for (int dt = 0; dt < 2; dt++)
#pragma unroll
      for (int g = 0; g < 4; g++) {
        u16 b0 = f2bf(o2[dt][4 * g + 0] * inv), b1 = f2bf(o2[dt][4 * g + 1] * inv);
        u16 b2 = f2bf(o2[dt][4 * g + 2] * inv), b3 = f2bf(o2[dt][4 * g + 3] * inv);
        u32 dw0 = (u32)b0 | ((u32)b1 << 16);
        u32 dw1 = (u32)b2 | ((u32)b3 << 16);
        *reinterpret_cast<uint2*>(&yw[ybase + dt * 32 + 8 * g + 4 * hi]) = make_uint2(dw0, dw1);
      }
  }
  gridbar(bar, 3 * GRID_N);

  // ---------------- phase 3: oproj (512 active blocks) ----------------
  if (bid < 512) {
    u16* Al0 = (u16*)(smem);
    u16* Al1 = (u16*)(smem + 4096);
    u16* Bl0 = (u16*)(smem + 8192);
    u16* Bl1 = (u16*)(smem + 16384);
    const int nb = bid & 7, mb = bid >> 3;
    const int wm = wave & 1, wn = wave >> 1;

    const int srow = lane >> 2, sch = lane & 3;
    const int gch = sch ^ ((srow >> 1) & 3);
    const u16* gA = yw  + (size_t)(mb * 64 + wave * 16 + srow) * D_EMB + gch * 8;
    const u16* gB = Wot + (size_t)(nb * 128 + wave * 32 + srow) * D_EMB + gch * 8;

    auto stage = [&](int kb, u16* AL, u16* BL) {
      char* lA = (char*)AL + wave * 1024;
      char* lB = (char*)BL + wave * 2048;
      __builtin_amdgcn_global_load_lds(GLB(gA + kb), LDSP(lA), 16, 0, 0);
#pragma unroll
      for (int it = 0; it < 2; it++)
        __builtin_amdgcn_global_load_lds(GLB(gB + (size_t)it * 16 * D_EMB + kb), LDSP(lB + it * 1024), 16, 0, 0);
    };

    f32x4 acc[2][4] = {};
    auto compute = [&](const u16* AL, const u16* BL) {
      bf16x8 af[2], bfr[4];
#pragma unroll
      for (int mt = 0; mt < 2; mt++) {
        int r = wm * 32 + mt * 16 + ln15;
        af[mt] = *reinterpret_cast<const bf16x8*>(&AL[r * 32 + ((quad ^ ((r >> 1) & 3)) * 8)]);
      }
#pragma unroll
      for (int nt = 0; nt < 4; nt++) {
        int r = wn * 64 + nt * 16 + ln15;
        bfr[nt] = *reinterpret_cast<const bf16x8*>(&BL[r * 32 + ((quad ^ ((r >> 1) & 3)) * 8)]);
      }
#pragma unroll
      for (int mt = 0; mt < 2; mt++)
#pragma unroll
        for (int nt = 0; nt < 4; nt++)
          acc[mt][nt] = __builtin_amdgcn_mfma_f32_16x16x32_bf16(af[mt], bfr[nt], acc[mt][nt], 0, 0, 0);
    };

    stage(0, Al0, Bl0);
    for (int kb = 0; kb < D_EMB; kb += 64) {
      __syncthreads();
      stage(kb + 32, Al1, Bl1);
      compute(Al0, Bl0);
      __syncthreads();
      if (kb + 64 < D_EMB) stage(kb + 64, Al0, Bl0);
      compute(Al1, Bl1);
    }

#pragma unroll
    for (int mt = 0; mt < 2; mt++)
#pragma unroll
      for (int nt = 0; nt < 4; nt++)
#pragma unroll
        for (int i = 0; i < 4; i++) {
          int rr = mb * 64 + wm * 32 + mt * 16 + quad * 4 + i;
          int c  = nb * 128 + wn * 64 + nt * 16 + ln15;
          out[(size_t)rr * D_EMB + c] = acc[mt][nt][i];
        }
  }
}

extern "C" void kernel_launch(void* const* d_in, const int* in_sizes, int n_in,
                              void* d_out, int out_size, void* d_ws, size_t ws_size,
                              hipStream_t stream) {
  const float* x    = (const float*)d_in[0];
  const float* e    = (const float*)d_in[1];
  const float* W_en = (const float*)d_in[2];
  const float* W_q  = (const float*)d_in[3];
  const float* W_o  = (const float*)d_in[4];
  float* out = (float*)d_out;

  // Layout (48 MB + 64 B high-water):
  // [0,8) xb (phase 0/1) ALIASED with yw (phase 2/3) — lifetimes barrier-separated.
  char* w = (char*)d_ws;
  u16* xb   = (u16*)(w);                 // phases 0-1
  u16* yw   = (u16*)(w);                 // phases 2-3 (alias, dead xb)
  u16* eb   = (u16*)(w + (8u  << 20));
  u16* Wqt  = (u16*)(w + (16u << 20));
  u16* Went = (u16*)(w + (18u << 20));
  u16* Wot  = (u16*)(w + (22u << 20));
  u16* qw   = (u16*)(w + (24u << 20));
  u16* kw   = (u16*)(w + (32u << 20));
  u16* vT   = (u16*)(w + (40u << 20));
  u32* bar  = (u32*)(w + (48u << 20));   // in-bounds barrier counter

  hipMemsetAsync(bar, 0, 64, stream);    // zero counter each launch (graph-safe)
  mega_kernel<<<GRID_N, 256, 0, stream>>>(x, e, W_q, W_en, W_o,
                                          xb, eb, Wqt, Went, Wot,
                                          qw, kw, vT, yw, out, bar);
}

// Round 12
// 213.212 us; speedup vs baseline: 2.7437x; 2.1188x over previous
//
#include <hip/hip_runtime.h>

typedef unsigned short u16;
typedef unsigned int u32;
typedef __bf16 bf16x8 __attribute__((ext_vector_type(8)));
typedef float f32x4 __attribute__((ext_vector_type(4)));
typedef float f32x16 __attribute__((ext_vector_type(16)));

#define D_EMB 1024
#define T_SEQ 2048
#define NH 16
#define HD 64

#define GLB(p) ((const __attribute__((address_space(1))) unsigned int*)(p))
#define LDSP(p) ((__attribute__((address_space(3))) unsigned int*)(p))

__device__ __forceinline__ u16 f2bf(float f) {
  union { float f; unsigned u; } c; c.f = f;
  unsigned u = c.u;
  unsigned r = (u + 0x7FFFu + ((u >> 16) & 1u)) >> 16;
  return (u16)r;
}
__device__ __forceinline__ u32 fbits(float f) {
  union { float f; unsigned u; } c; c.f = f; return c.u;
}

// ---------------- fused prep ----------------
__global__ __launch_bounds__(256) void prep_kernel(
    const float* __restrict__ x, const float* __restrict__ e,
    const float* __restrict__ W_q, const float* __restrict__ W_en, const float* __restrict__ W_o,
    u16* __restrict__ xb, u16* __restrict__ eb,
    u16* __restrict__ Wqt, u16* __restrict__ Went, u16* __restrict__ Wot) {
  __shared__ float tile[32][33];
  const int bid = blockIdx.x, tid = threadIdx.x;
  if (bid < 8192) {
    const float* in = (bid < 4096) ? x : e;
    u16* out = (bid < 4096) ? xb : eb;
    int i = (bid & 4095) * 256 + tid;
    float4 v = reinterpret_cast<const float4*>(in)[i];
    ushort4 o;
    o.x = f2bf(v.x); o.y = f2bf(v.y); o.z = f2bf(v.z); o.w = f2bf(v.w);
    reinterpret_cast<ushort4*>(out)[i] = o;
    return;
  }
  const float* in; u16* out; int K, N, bx, by;
  int rem = bid - 8192;
  if (rem < 1024)      { in = W_q;  out = Wqt;  K = 1024; N = 1024; bx = rem & 31; by = rem >> 5; }
  else if (rem < 3072) { int r2 = rem - 1024; in = W_en; out = Went; K = 1024; N = 2048; bx = r2 & 63; by = r2 >> 6; }
  else                 { int r3 = rem - 3072; in = W_o;  out = Wot;  K = 1024; N = 1024; bx = r3 & 31; by = r3 >> 5; }
  int tx = tid & 31, ty = tid >> 5;
  int n0 = bx * 32, k0 = by * 32;
#pragma unroll
  for (int s = 0; s < 4; s++)
    tile[ty + 8 * s][tx] = in[(size_t)(k0 + ty + 8 * s) * N + n0 + tx];
  __syncthreads();
#pragma unroll
  for (int s = 0; s < 4; s++)
    out[(size_t)(n0 + ty + 8 * s) * K + k0 + tx] = f2bf(tile[tx][ty + 8 * s]);
}

// ---------------- fused QKV projection GEMM: 64x128 tile, BK=32, dbuf distinct arrays ----
// Clone of the proven oproj skeleton (LDS 24 KB -> ~5 blocks/CU) + proj's scatter epilogue.
// grid (nb=24, mb=64).
__global__ __launch_bounds__(256) void proj_kernel(
    const u16* __restrict__ xb, const u16* __restrict__ eb,
    const u16* __restrict__ Wqt, const u16* __restrict__ Went,
    u16* __restrict__ qw, u16* __restrict__ kw, u16* __restrict__ vTw) {
  __shared__ u16 Al0[64 * 32], Al1[64 * 32];
  __shared__ u16 Bl0[128 * 32], Bl1[128 * 32];
  const int tid = threadIdx.x;
  const int nb = blockIdx.x, mb = blockIdx.y;
  const int wave = tid >> 6, lane = tid & 63;
  const int ln15 = lane & 15, quad = lane >> 4;
  const int wm = wave & 1, wn = wave >> 1;

  const u16* A = (nb < 8) ? xb : eb;
  const u16* Wt = (nb < 8) ? (Wqt + (size_t)nb * 128 * D_EMB)
                           : (Went + ((size_t)nb * 128 - D_EMB) * D_EMB);

  const int srow = lane >> 2, sch = lane & 3;
  const int gch = sch ^ ((srow >> 1) & 3);
  const u16* gA = A  + (size_t)(mb * 64 + wave * 16 + srow) * D_EMB + gch * 8;
  const u16* gB = Wt + (size_t)(wave * 32 + srow) * D_EMB + gch * 8;

  auto stage = [&](int kb, u16* AL, u16* BL) {
    char* lA = (char*)AL + wave * 1024;
    char* lB = (char*)BL + wave * 2048;
    __builtin_amdgcn_global_load_lds(GLB(gA + kb), LDSP(lA), 16, 0, 0);
#pragma unroll
    for (int it = 0; it < 2; it++)
      __builtin_amdgcn_global_load_lds(GLB(gB + (size_t)it * 16 * D_EMB + kb), LDSP(lB + it * 1024), 16, 0, 0);
  };

  f32x4 acc[2][4] = {};

  auto compute = [&](const u16* AL, const u16* BL) {
    bf16x8 af[2], bfr[4];
#pragma unroll
    for (int mt = 0; mt < 2; mt++) {
      int r = wm * 32 + mt * 16 + ln15;
      af[mt] = *reinterpret_cast<const bf16x8*>(&AL[r * 32 + ((quad ^ ((r >> 1) & 3)) * 8)]);
    }
#pragma unroll
    for (int nt = 0; nt < 4; nt++) {
      int r = wn * 64 + nt * 16 + ln15;
      bfr[nt] = *reinterpret_cast<const bf16x8*>(&BL[r * 32 + ((quad ^ ((r >> 1) & 3)) * 8)]);
    }
#pragma unroll
    for (int mt = 0; mt < 2; mt++)
#pragma unroll
      for (int nt = 0; nt < 4; nt++)
        acc[mt][nt] = __builtin_amdgcn_mfma_f32_16x16x32_bf16(af[mt], bfr[nt], acc[mt][nt], 0, 0, 0);
  };

  stage(0, Al0, Bl0);
  for (int kb = 0; kb < D_EMB; kb += 64) {
    __syncthreads();
    stage(kb + 32, Al1, Bl1);
    compute(Al0, Bl0);
    __syncthreads();
    if (kb + 64 < D_EMB) stage(kb + 64, Al0, Bl0);
    compute(Al1, Bl1);
  }

  const float QSCL = 0.125f * 1.44269504f;
#pragma unroll
  for (int mt = 0; mt < 2; mt++) {
#pragma unroll
    for (int nt = 0; nt < 4; nt++) {
#pragma unroll
      for (int i = 0; i < 4; i++) {
        int rr = mb * 64 + wm * 32 + mt * 16 + quad * 4 + i;
        int c  = nb * 128 + wn * 64 + nt * 16 + ln15;
        float v = acc[mt][nt][i];
        int b = rr >> 11, t = rr & 2047;
        if (c < D_EMB) {
          int h = c >> 6, d = c & 63;
          qw[(((size_t)(b * NH + h)) * T_SEQ + t) * HD + d] = f2bf(v * QSCL);
        } else if (c < 2 * D_EMB) {
          int cc = c - D_EMB; int h = cc >> 6, d = cc & 63;
          kw[(((size_t)(b * NH + h)) * T_SEQ + t) * HD + d] = f2bf(v);
        } else {
          int cc = c - 2 * D_EMB; int h = cc >> 6, d = cc & 63;
          vTw[(((size_t)(b * NH + h)) * HD + d) * T_SEQ + t] = f2bf(v);
        }
      }
    }
  }
}

// ---------------- flash attention (R8 body; grid swizzled bh-fast for XCD L2 locality) ----
// grid (bh=32, qt=16): linear bid = bh + 32*qt -> XCD = bh%8, so all 16 qt-blocks of a
// head share one XCD's L2 (4 heads x 512 KB = 2 MB < 4 MB per-XCD L2).
__global__ __launch_bounds__(256) void attn_kernel(
    const u16* __restrict__ q, const u16* __restrict__ k,
    const u16* __restrict__ vT, u16* __restrict__ y) {
  __shared__ u16 Kl0[64][64], Vl0[64][64];
  __shared__ u16 Kl1[64][64], Vl1[64][64];
  __shared__ u16 Pl[4][32][64];

  const int bh = blockIdx.x;        // fast dim -> XCD-pinned per head
  const int qt = blockIdx.y;
  const int tid = threadIdx.x;
  const int wave = tid >> 6, lane = tid & 63;
  const int q32 = lane & 31, hi = lane >> 5;
  const int b = bh >> 4, h = bh & 15;

  const int qrow = qt * 128 + wave * 32 + q32;
  const u16* qbase = q + ((size_t)bh * T_SEQ + qrow) * HD;
  bf16x8 qf[4];
#pragma unroll
  for (int s = 0; s < 4; s++)
    qf[s] = *reinterpret_cast<const bf16x8*>(qbase + s * 16 + hi * 8);

  f32x16 o2[2] = {};
  float lp = 0.f;

  const int srow = (lane >> 3) & 7;
  const int gch  = (lane & 7) ^ srow;
  const u16* kg0 = k  + ((size_t)bh * T_SEQ + wave * 16 + srow) * HD + gch * 8;
  const u16* vg0 = vT + ((size_t)bh * HD + wave * 16 + srow) * T_SEQ + gch * 8;

  auto issue_dma = [&](int t, u16 (*KL)[64], u16 (*VL)[64]) {
    char* klb = (char*)KL + wave * 2048;
    char* vlb = (char*)VL + wave * 2048;
    const u16* kp = kg0 + (size_t)t * 64 * HD;
    const u16* vp = vg0 + t * 64;
    __builtin_amdgcn_global_load_lds(GLB(kp),             LDSP(klb),        16, 0, 0);
    __builtin_amdgcn_global_load_lds(GLB(kp + 8 * HD),    LDSP(klb + 1024), 16, 0, 0);
    __builtin_amdgcn_global_load_lds(GLB(vp),             LDSP(vlb),        16, 0, 0);
    __builtin_amdgcn_global_load_lds(GLB(vp + 8 * T_SEQ), LDSP(vlb + 1024), 16, 0, 0);
  };

  auto body = [&](const u16 (*KL)[64], const u16 (*VL)[64]) {
    f32x16 s2[2] = {};
#pragma unroll
    for (int s = 0; s < 4; s++)
#pragma unroll
      for (int kt2 = 0; kt2 < 2; kt2++) {
        int r = kt2 * 32 + q32;
        bf16x8 kf = *reinterpret_cast<const bf16x8*>(&KL[r][(((s * 2 + hi) ^ (r & 7)) * 8)]);
        s2[kt2] = __builtin_amdgcn_mfma_f32_32x32x16_bf16(kf, qf[s], s2[kt2], 0, 0, 0);
      }

#pragma unroll
    for (int kt2 = 0; kt2 < 2; kt2++)
#pragma unroll
      for (int g = 0; g < 4; g++) {
        float p0 = __builtin_amdgcn_exp2f(s2[kt2][4 * g + 0]);
        float p1 = __builtin_amdgcn_exp2f(s2[kt2][4 * g + 1]);
        float p2 = __builtin_amdgcn_exp2f(s2[kt2][4 * g + 2]);
        float p3 = __builtin_amdgcn_exp2f(s2[kt2][4 * g + 3]);
        lp += (p0 + p1) + (p2 + p3);
        u32 dw0 = __builtin_amdgcn_perm(fbits(p1), fbits(p0), 0x07060302u);
        u32 dw1 = __builtin_amdgcn_perm(fbits(p3), fbits(p2), 0x07060302u);
        int phys = (kt2 * 4 + g) ^ (q32 & 7);
        *reinterpret_cast<uint2*>(&Pl[wave][q32][phys * 8 + 4 * hi]) = make_uint2(dw0, dw1);
      }
    asm volatile("s_waitcnt lgkmcnt(0)" ::: "memory");

#pragma unroll
    for (int s = 0; s < 4; s++) {
      bf16x8 pf = *reinterpret_cast<const bf16x8*>(
          &Pl[wave][q32][(((s * 2 + hi) ^ (q32 & 7)) * 8)]);
#pragma unroll
      for (int dt = 0; dt < 2; dt++) {
        int r = dt * 32 + q32;
        bf16x8 vf = *reinterpret_cast<const bf16x8*>(&VL[r][(((s * 2 + hi) ^ (r & 7)) * 8)]);
        o2[dt] = __builtin_amdgcn_mfma_f32_32x32x16_bf16(vf, pf, o2[dt], 0, 0, 0);
      }
    }
  };

  issue_dma(0, Kl0, Vl0);
  for (int t = 0; t < 32; t += 2) {
    __syncthreads();
    issue_dma(t + 1, Kl1, Vl1);
    body(Kl0, Vl0);
    __syncthreads();
    if (t + 2 < 32) issue_dma(t + 2, Kl0, Vl0);
    body(Kl1, Vl1);
  }

  lp += __shfl_xor(lp, 32, 64);
  const float inv = 1.0f / lp;

  const size_t ybase = ((size_t)b * T_SEQ + qrow) * D_EMB + h * 64;
#pragma unroll
  for (int dt = 0; dt < 2; dt++)
#pragma unroll
    for (int g = 0; g < 4; g++) {
      u16 b0 = f2bf(o2[dt][4 * g + 0] * inv), b1 = f2bf(o2[dt][4 * g + 1] * inv);
      u16 b2 = f2bf(o2[dt][4 * g + 2] * inv), b3 = f2bf(o2[dt][4 * g + 3] * inv);
      u32 dw0 = (u32)b0 | ((u32)b1 << 16);
      u32 dw1 = (u32)b2 | ((u32)b3 << 16);
      *reinterpret_cast<uint2*>(&y[ybase + dt * 32 + 8 * g + 4 * hi]) = make_uint2(dw0, dw1);
    }
}

// ---------------- output projection: 64x128 tile, BK=32, dbuf distinct arrays ----------------
__global__ __launch_bounds__(256) void oproj_kernel(
    const u16* __restrict__ yw, const u16* __restrict__ Wot, float* __restrict__ out) {
  __shared__ u16 Al0[64 * 32], Al1[64 * 32];
  __shared__ u16 Bl0[128 * 32], Bl1[128 * 32];
  const int tid = threadIdx.x;
  const int nb = blockIdx.x, mb = blockIdx.y;
  const int wave = tid >> 6, lane = tid & 63;
  const int ln15 = lane & 15, quad = lane >> 4;
  const int wm = wave & 1, wn = wave >> 1;

  const int srow = lane >> 2, sch = lane & 3;
  const int gch = sch ^ ((srow >> 1) & 3);
  const u16* gA = yw  + (size_t)(mb * 64 + wave * 16 + srow) * D_EMB + gch * 8;
  const u16* gB = Wot + (size_t)(nb * 128 + wave * 32 + srow) * D_EMB + gch * 8;

  auto stage = [&](int kb, u16* AL, u16* BL) {
    char* lA = (char*)AL + wave * 1024;
    char* lB = (char*)BL + wave * 2048;
    __builtin_amdgcn_global_load_lds(GLB(gA + kb), LDSP(lA), 16, 0, 0);
#pragma unroll
    for (int it = 0; it < 2; it++)
      __builtin_amdgcn_global_load_lds(GLB(gB + (size_t)it * 16 * D_EMB + kb), LDSP(lB + it * 1024), 16, 0, 0);
  };

  f32x4 acc[2][4] = {};

  auto compute = [&](const u16* AL, const u16* BL) {
    bf16x8 af[2], bfr[4];
#pragma unroll
    for (int mt = 0; mt < 2; mt++) {
      int r = wm * 32 + mt * 16 + ln15;
      af[mt] = *reinterpret_cast<const bf16x8*>(&AL[r * 32 + ((quad ^ ((r >> 1) & 3)) * 8)]);
    }
#pragma unroll
    for (int nt = 0; nt < 4; nt++) {
      int r = wn * 64 + nt * 16 + ln15;
      bfr[nt] = *reinterpret_cast<const bf16x8*>(&BL[r * 32 + ((quad ^ ((r >> 1) & 3)) * 8)]);
    }
#pragma unroll
    for (int mt = 0; mt < 2; mt++)
#pragma unroll
      for (int nt = 0; nt < 4; nt++)
        acc[mt][nt] = __builtin_amdgcn_mfma_f32_16x16x32_bf16(af[mt], bfr[nt], acc[mt][nt], 0, 0, 0);
  };

  stage(0, Al0, Bl0);
  for (int kb = 0; kb < D_EMB; kb += 64) {
    __syncthreads();
    stage(kb + 32, Al1, Bl1);
    compute(Al0, Bl0);
    __syncthreads();
    if (kb + 64 < D_EMB) stage(kb + 64, Al0, Bl0);
    compute(Al1, Bl1);
  }

#pragma unroll
  for (int mt = 0; mt < 2; mt++)
#pragma unroll
    for (int nt = 0; nt < 4; nt++)
#pragma unroll
      for (int i = 0; i < 4; i++) {
        int rr = mb * 64 + wm * 32 + mt * 16 + quad * 4 + i;
        int c  = nb * 128 + wn * 64 + nt * 16 + ln15;
        out[(size_t)rr * D_EMB + c] = acc[mt][nt][i];
      }
}

extern "C" void kernel_launch(void* const* d_in, const int* in_sizes, int n_in,
                              void* d_out, int out_size, void* d_ws, size_t ws_size,
                              hipStream_t stream) {
  const float* x    = (const float*)d_in[0];
  const float* e    = (const float*)d_in[1];
  const float* W_en = (const float*)d_in[2];
  const float* W_q  = (const float*)d_in[3];
  const float* W_o  = (const float*)d_in[4];
  float* out = (float*)d_out;

  char* w = (char*)d_ws;
  u16* xb   = (u16*)(w);
  u16* eb   = (u16*)(w + (8u  << 20));
  u16* Wqt  = (u16*)(w + (16u << 20));
  u16* Went = (u16*)(w + (18u << 20));
  u16* Wot  = (u16*)(w + (22u << 20));
  u16* qw   = (u16*)(w + (24u << 20));
  u16* kw   = (u16*)(w + (32u << 20));
  u16* vT   = (u16*)(w + (40u << 20));
  u16* yw   = (u16*)(w + (48u << 20));

  prep_kernel<<<12288, 256, 0, stream>>>(x, e, W_q, W_en, W_o, xb, eb, Wqt, Went, Wot);
  proj_kernel<<<dim3(24, 64), 256, 0, stream>>>(xb, eb, Wqt, Went, qw, kw, vT);
  attn_kernel<<<dim3(32, 16), 256, 0, stream>>>(qw, kw, vT, yw);
  oproj_kernel<<<dim3(8, 64), 256, 0, stream>>>(yw, Wot, out);
}

// Round 13
// 205.594 us; speedup vs baseline: 2.8454x; 1.0371x over previous
//
#include <hip/hip_runtime.h>

typedef unsigned short u16;
typedef unsigned int u32;
typedef __bf16 bf16x8 __attribute__((ext_vector_type(8)));
typedef float f32x4 __attribute__((ext_vector_type(4)));
typedef float f32x16 __attribute__((ext_vector_type(16)));

#define D_EMB 1024
#define T_SEQ 2048
#define NH 16
#define HD 64

#define GLB(p) ((const __attribute__((address_space(1))) unsigned int*)(p))
#define LDSP(p) ((__attribute__((address_space(3))) unsigned int*)(p))

__device__ __forceinline__ u16 f2bf(float f) {
  union { float f; unsigned u; } c; c.f = f;
  unsigned u = c.u;
  unsigned r = (u + 0x7FFFu + ((u >> 16) & 1u)) >> 16;
  return (u16)r;
}
__device__ __forceinline__ u32 fbits(float f) {
  union { float f; unsigned u; } c; c.f = f; return c.u;
}

// ---------------- fused prep ----------------
__global__ __launch_bounds__(256) void prep_kernel(
    const float* __restrict__ x, const float* __restrict__ e,
    const float* __restrict__ W_q, const float* __restrict__ W_en, const float* __restrict__ W_o,
    u16* __restrict__ xb, u16* __restrict__ eb,
    u16* __restrict__ Wqt, u16* __restrict__ Went, u16* __restrict__ Wot) {
  __shared__ float tile[32][33];
  const int bid = blockIdx.x, tid = threadIdx.x;
  if (bid < 8192) {
    const float* in = (bid < 4096) ? x : e;
    u16* out = (bid < 4096) ? xb : eb;
    int i = (bid & 4095) * 256 + tid;
    float4 v = reinterpret_cast<const float4*>(in)[i];
    ushort4 o;
    o.x = f2bf(v.x); o.y = f2bf(v.y); o.z = f2bf(v.z); o.w = f2bf(v.w);
    reinterpret_cast<ushort4*>(out)[i] = o;
    return;
  }
  const float* in; u16* out; int K, N, bx, by;
  int rem = bid - 8192;
  if (rem < 1024)      { in = W_q;  out = Wqt;  K = 1024; N = 1024; bx = rem & 31; by = rem >> 5; }
  else if (rem < 3072) { int r2 = rem - 1024; in = W_en; out = Went; K = 1024; N = 2048; bx = r2 & 63; by = r2 >> 6; }
  else                 { int r3 = rem - 3072; in = W_o;  out = Wot;  K = 1024; N = 1024; bx = r3 & 31; by = r3 >> 5; }
  int tx = tid & 31, ty = tid >> 5;
  int n0 = bx * 32, k0 = by * 32;
#pragma unroll
  for (int s = 0; s < 4; s++)
    tile[ty + 8 * s][tx] = in[(size_t)(k0 + ty + 8 * s) * N + n0 + tx];
  __syncthreads();
#pragma unroll
  for (int s = 0; s < 4; s++)
    out[(size_t)(n0 + ty + 8 * s) * K + k0 + tx] = f2bf(tile[tx][ty + 8 * s]);
}

// ---------------- fused QKV projection GEMM: 128x128, BK=32, dbuf (R8 body) ----------------
// Grid swapped to (mb=32 fast, nb=24): XCD = bid%8 = mb%8 pins A-tiles per-XCD
// (A read ~once from HBM; small weights re-read via L3) — shorter DMA drains.
__global__ __launch_bounds__(256) void proj_kernel(
    const u16* __restrict__ xb, const u16* __restrict__ eb,
    const u16* __restrict__ Wqt, const u16* __restrict__ Went,
    u16* __restrict__ qw, u16* __restrict__ kw, u16* __restrict__ vTw) {
  __shared__ u16 Al0[128 * 32], Bl0[128 * 32];
  __shared__ u16 Al1[128 * 32], Bl1[128 * 32];
  const int tid = threadIdx.x;
  const int mb = blockIdx.x, nb = blockIdx.y;   // mb fast -> XCD-pinned A
  const int wave = tid >> 6, lane = tid & 63;
  const int ln15 = lane & 15, quad = lane >> 4;
  const int wm = wave & 1, wn = wave >> 1;

  const u16* A = (nb < 8) ? xb : eb;
  const u16* Wt = (nb < 8) ? (Wqt + (size_t)nb * 128 * D_EMB)
                           : (Went + ((size_t)nb * 128 - D_EMB) * D_EMB);

  const int srow = lane >> 2, sch = lane & 3;
  const int gch = sch ^ ((srow >> 1) & 3);
  const u16* gA = A + (size_t)(mb * 128 + wave * 32 + srow) * D_EMB + gch * 8;
  const u16* gB = Wt + (size_t)(wave * 32 + srow) * D_EMB + gch * 8;

  auto stage = [&](int kb, u16* AL, u16* BL) {
    char* lA = (char*)AL + wave * 2048;
    char* lB = (char*)BL + wave * 2048;
#pragma unroll
    for (int it = 0; it < 2; it++) {
      __builtin_amdgcn_global_load_lds(GLB(gA + (size_t)it * 16 * D_EMB + kb), LDSP(lA + it * 1024), 16, 0, 0);
      __builtin_amdgcn_global_load_lds(GLB(gB + (size_t)it * 16 * D_EMB + kb), LDSP(lB + it * 1024), 16, 0, 0);
    }
  };

  f32x4 acc[4][4] = {};

  auto compute = [&](const u16* AL, const u16* BL) {
    bf16x8 af[4], bfr[4];
#pragma unroll
    for (int mt = 0; mt < 4; mt++) {
      int r = wm * 64 + mt * 16 + ln15;
      af[mt] = *reinterpret_cast<const bf16x8*>(&AL[r * 32 + ((quad ^ ((r >> 1) & 3)) * 8)]);
    }
#pragma unroll
    for (int nt = 0; nt < 4; nt++) {
      int r = wn * 64 + nt * 16 + ln15;
      bfr[nt] = *reinterpret_cast<const bf16x8*>(&BL[r * 32 + ((quad ^ ((r >> 1) & 3)) * 8)]);
    }
#pragma unroll
    for (int mt = 0; mt < 4; mt++)
#pragma unroll
      for (int nt = 0; nt < 4; nt++)
        acc[mt][nt] = __builtin_amdgcn_mfma_f32_16x16x32_bf16(af[mt], bfr[nt], acc[mt][nt], 0, 0, 0);
  };

  stage(0, Al0, Bl0);
  for (int kb = 0; kb < D_EMB; kb += 64) {
    __syncthreads();
    stage(kb + 32, Al1, Bl1);
    compute(Al0, Bl0);
    __syncthreads();
    if (kb + 64 < D_EMB) stage(kb + 64, Al0, Bl0);
    compute(Al1, Bl1);
  }

  const float QSCL = 0.125f * 1.44269504f;
#pragma unroll
  for (int mt = 0; mt < 4; mt++) {
#pragma unroll
    for (int nt = 0; nt < 4; nt++) {
#pragma unroll
      for (int i = 0; i < 4; i++) {
        int rr = mb * 128 + wm * 64 + mt * 16 + quad * 4 + i;
        int c  = nb * 128 + wn * 64 + nt * 16 + ln15;
        float v = acc[mt][nt][i];
        int b = rr >> 11, t = rr & 2047;
        if (c < D_EMB) {
          int h = c >> 6, d = c & 63;
          qw[(((size_t)(b * NH + h)) * T_SEQ + t) * HD + d] = f2bf(v * QSCL);
        } else if (c < 2 * D_EMB) {
          int cc = c - D_EMB; int h = cc >> 6, d = cc & 63;
          kw[(((size_t)(b * NH + h)) * T_SEQ + t) * HD + d] = f2bf(v);
        } else {
          int cc = c - 2 * D_EMB; int h = cc >> 6, d = cc & 63;
          vTw[(((size_t)(b * NH + h)) * HD + d) * T_SEQ + t] = f2bf(v);
        }
      }
    }
  }
}

// ---------------- flash attention (R12: bh-fast grid for XCD L2 locality) ----------------
__global__ __launch_bounds__(256) void attn_kernel(
    const u16* __restrict__ q, const u16* __restrict__ k,
    const u16* __restrict__ vT, u16* __restrict__ y) {
  __shared__ u16 Kl0[64][64], Vl0[64][64];
  __shared__ u16 Kl1[64][64], Vl1[64][64];
  __shared__ u16 Pl[4][32][64];

  const int bh = blockIdx.x;
  const int qt = blockIdx.y;
  const int tid = threadIdx.x;
  const int wave = tid >> 6, lane = tid & 63;
  const int q32 = lane & 31, hi = lane >> 5;
  const int b = bh >> 4, h = bh & 15;

  const int qrow = qt * 128 + wave * 32 + q32;
  const u16* qbase = q + ((size_t)bh * T_SEQ + qrow) * HD;
  bf16x8 qf[4];
#pragma unroll
  for (int s = 0; s < 4; s++)
    qf[s] = *reinterpret_cast<const bf16x8*>(qbase + s * 16 + hi * 8);

  f32x16 o2[2] = {};
  float lp = 0.f;

  const int srow = (lane >> 3) & 7;
  const int gch  = (lane & 7) ^ srow;
  const u16* kg0 = k  + ((size_t)bh * T_SEQ + wave * 16 + srow) * HD + gch * 8;
  const u16* vg0 = vT + ((size_t)bh * HD + wave * 16 + srow) * T_SEQ + gch * 8;

  auto issue_dma = [&](int t, u16 (*KL)[64], u16 (*VL)[64]) {
    char* klb = (char*)KL + wave * 2048;
    char* vlb = (char*)VL + wave * 2048;
    const u16* kp = kg0 + (size_t)t * 64 * HD;
    const u16* vp = vg0 + t * 64;
    __builtin_amdgcn_global_load_lds(GLB(kp),             LDSP(klb),        16, 0, 0);
    __builtin_amdgcn_global_load_lds(GLB(kp + 8 * HD),    LDSP(klb + 1024), 16, 0, 0);
    __builtin_amdgcn_global_load_lds(GLB(vp),             LDSP(vlb),        16, 0, 0);
    __builtin_amdgcn_global_load_lds(GLB(vp + 8 * T_SEQ), LDSP(vlb + 1024), 16, 0, 0);
  };

  auto body = [&](const u16 (*KL)[64], const u16 (*VL)[64]) {
    f32x16 s2[2] = {};
#pragma unroll
    for (int s = 0; s < 4; s++)
#pragma unroll
      for (int kt2 = 0; kt2 < 2; kt2++) {
        int r = kt2 * 32 + q32;
        bf16x8 kf = *reinterpret_cast<const bf16x8*>(&KL[r][(((s * 2 + hi) ^ (r & 7)) * 8)]);
        s2[kt2] = __builtin_amdgcn_mfma_f32_32x32x16_bf16(kf, qf[s], s2[kt2], 0, 0, 0);
      }

#pragma unroll
    for (int kt2 = 0; kt2 < 2; kt2++)
#pragma unroll
      for (int g = 0; g < 4; g++) {
        float p0 = __builtin_amdgcn_exp2f(s2[kt2][4 * g + 0]);
        float p1 = __builtin_amdgcn_exp2f(s2[kt2][4 * g + 1]);
        float p2 = __builtin_amdgcn_exp2f(s2[kt2][4 * g + 2]);
        float p3 = __builtin_amdgcn_exp2f(s2[kt2][4 * g + 3]);
        lp += (p0 + p1) + (p2 + p3);
        u32 dw0 = __builtin_amdgcn_perm(fbits(p1), fbits(p0), 0x07060302u);
        u32 dw1 = __builtin_amdgcn_perm(fbits(p3), fbits(p2), 0x07060302u);
        int phys = (kt2 * 4 + g) ^ (q32 & 7);
        *reinterpret_cast<uint2*>(&Pl[wave][q32][phys * 8 + 4 * hi]) = make_uint2(dw0, dw1);
      }
    asm volatile("s_waitcnt lgkmcnt(0)" ::: "memory");

#pragma unroll
    for (int s = 0; s < 4; s++) {
      bf16x8 pf = *reinterpret_cast<const bf16x8*>(
          &Pl[wave][q32][(((s * 2 + hi) ^ (q32 & 7)) * 8)]);
#pragma unroll
      for (int dt = 0; dt < 2; dt++) {
        int r = dt * 32 + q32;
        bf16x8 vf = *reinterpret_cast<const bf16x8*>(&VL[r][(((s * 2 + hi) ^ (r & 7)) * 8)]);
        o2[dt] = __builtin_amdgcn_mfma_f32_32x32x16_bf16(vf, pf, o2[dt], 0, 0, 0);
      }
    }
  };

  issue_dma(0, Kl0, Vl0);
  for (int t = 0; t < 32; t += 2) {
    __syncthreads();
    issue_dma(t + 1, Kl1, Vl1);
    body(Kl0, Vl0);
    __syncthreads();
    if (t + 2 < 32) issue_dma(t + 2, Kl0, Vl0);
    body(Kl1, Vl1);
  }

  lp += __shfl_xor(lp, 32, 64);
  const float inv = 1.0f / lp;

  const size_t ybase = ((size_t)b * T_SEQ + qrow) * D_EMB + h * 64;
#pragma unroll
  for (int dt = 0; dt < 2; dt++)
#pragma unroll
    for (int g = 0; g < 4; g++) {
      u16 b0 = f2bf(o2[dt][4 * g + 0] * inv), b1 = f2bf(o2[dt][4 * g + 1] * inv);
      u16 b2 = f2bf(o2[dt][4 * g + 2] * inv), b3 = f2bf(o2[dt][4 * g + 3] * inv);
      u32 dw0 = (u32)b0 | ((u32)b1 << 16);
      u32 dw1 = (u32)b2 | ((u32)b3 << 16);
      *reinterpret_cast<uint2*>(&y[ybase + dt * 32 + 8 * g + 4 * hi]) = make_uint2(dw0, dw1);
    }
}

// ---------------- output projection: 64x128 tile, BK=32, dbuf distinct arrays ----------------
__global__ __launch_bounds__(256) void oproj_kernel(
    const u16* __restrict__ yw, const u16* __restrict__ Wot, float* __restrict__ out) {
  __shared__ u16 Al0[64 * 32], Al1[64 * 32];
  __shared__ u16 Bl0[128 * 32], Bl1[128 * 32];
  const int tid = threadIdx.x;
  const int nb = blockIdx.x, mb = blockIdx.y;
  const int wave = tid >> 6, lane = tid & 63;
  const int ln15 = lane & 15, quad = lane >> 4;
  const int wm = wave & 1, wn = wave >> 1;

  const int srow = lane >> 2, sch = lane & 3;
  const int gch = sch ^ ((srow >> 1) & 3);
  const u16* gA = yw  + (size_t)(mb * 64 + wave * 16 + srow) * D_EMB + gch * 8;
  const u16* gB = Wot + (size_t)(nb * 128 + wave * 32 + srow) * D_EMB + gch * 8;

  auto stage = [&](int kb, u16* AL, u16* BL) {
    char* lA = (char*)AL + wave * 1024;
    char* lB = (char*)BL + wave * 2048;
    __builtin_amdgcn_global_load_lds(GLB(gA + kb), LDSP(lA), 16, 0, 0);
#pragma unroll
    for (int it = 0; it < 2; it++)
      __builtin_amdgcn_global_load_lds(GLB(gB + (size_t)it * 16 * D_EMB + kb), LDSP(lB + it * 1024), 16, 0, 0);
  };

  f32x4 acc[2][4] = {};

  auto compute = [&](const u16* AL, const u16* BL) {
    bf16x8 af[2], bfr[4];
#pragma unroll
    for (int mt = 0; mt < 2; mt++) {
      int r = wm * 32 + mt * 16 + ln15;
      af[mt] = *reinterpret_cast<const bf16x8*>(&AL[r * 32 + ((quad ^ ((r >> 1) & 3)) * 8)]);
    }
#pragma unroll
    for (int nt = 0; nt < 4; nt++) {
      int r = wn * 64 + nt * 16 + ln15;
      bfr[nt] = *reinterpret_cast<const bf16x8*>(&BL[r * 32 + ((quad ^ ((r >> 1) & 3)) * 8)]);
    }
#pragma unroll
    for (int mt = 0; mt < 2; mt++)
#pragma unroll
      for (int nt = 0; nt < 4; nt++)
        acc[mt][nt] = __builtin_amdgcn_mfma_f32_16x16x32_bf16(af[mt], bfr[nt], acc[mt][nt], 0, 0, 0);
  };

  stage(0, Al0, Bl0);
  for (int kb = 0; kb < D_EMB; kb += 64) {
    __syncthreads();
    stage(kb + 32, Al1, Bl1);
    compute(Al0, Bl0);
    __syncthreads();
    if (kb + 64 < D_EMB) stage(kb + 64, Al0, Bl0);
    compute(Al1, Bl1);
  }

#pragma unroll
  for (int mt = 0; mt < 2; mt++)
#pragma unroll
    for (int nt = 0; nt < 4; nt++)
#pragma unroll
      for (int i = 0; i < 4; i++) {
        int rr = mb * 64 + wm * 32 + mt * 16 + quad * 4 + i;
        int c  = nb * 128 + wn * 64 + nt * 16 + ln15;
        out[(size_t)rr * D_EMB + c] = acc[mt][nt][i];
      }
}

extern "C" void kernel_launch(void* const* d_in, const int* in_sizes, int n_in,
                              void* d_out, int out_size, void* d_ws, size_t ws_size,
                              hipStream_t stream) {
  const float* x    = (const float*)d_in[0];
  const float* e    = (const float*)d_in[1];
  const float* W_en = (const float*)d_in[2];
  const float* W_q  = (const float*)d_in[3];
  const float* W_o  = (const float*)d_in[4];
  float* out = (float*)d_out;

  char* w = (char*)d_ws;
  u16* xb   = (u16*)(w);
  u16* eb   = (u16*)(w + (8u  << 20));
  u16* Wqt  = (u16*)(w + (16u << 20));
  u16* Went = (u16*)(w + (18u << 20));
  u16* Wot  = (u16*)(w + (22u << 20));
  u16* qw   = (u16*)(w + (24u << 20));
  u16* kw   = (u16*)(w + (32u << 20));
  u16* vT   = (u16*)(w + (40u << 20));
  u16* yw   = (u16*)(w + (48u << 20));

  prep_kernel<<<12288, 256, 0, stream>>>(x, e, W_q, W_en, W_o, xb, eb, Wqt, Went, Wot);
  proj_kernel<<<dim3(32, 24), 256, 0, stream>>>(xb, eb, Wqt, Went, qw, kw, vT);
  attn_kernel<<<dim3(32, 16), 256, 0, stream>>>(qw, kw, vT, yw);
  oproj_kernel<<<dim3(8, 64), 256, 0, stream>>>(yw, Wot, out);
}